// Round 5
// baseline (1067.431 us; speedup 1.0000x reference)
//
#include <hip/hip_runtime.h>
#include <math.h>

// DEQ fixed-point via Broyden — single persistent kernel. B=256, D=2048, T=12.
// bf16 MFMA 3-term split GEMM (A=[hi|hi|lo], W=[hi;lo;hi], K=6144).
// 256 blocks x 1024 threads, 1 block/CU (VGPR<=128 enforced), manual grid
// barrier (device-scope atomics + fences). Block b owns batch row b:
// Us history in registers (always-12-slot algebra, zero-filled slots),
// VTs history in LDS. Azz (split x) and y (split-K partials) are the only
// cross-block traffic. ks = blockIdx&7 pins each K-slice to one XCD's L2.

#define DD 2048
#define KK 6144            // 3*DD
#define BB 256
#define BD (BB * DD)       // floats per [B,D] plane
#define TT 12
#define NBLK 256

typedef unsigned short ushort_t;
typedef __attribute__((ext_vector_type(8))) short short8;
typedef __attribute__((ext_vector_type(4))) float floatx4;

__device__ __forceinline__ ushort_t f2bf(float f) {
    unsigned int u = __float_as_uint(f);
    unsigned int r = (u + 0x7FFFu + ((u >> 16) & 1u)) >> 16;
    return (ushort_t)r;
}
__device__ __forceinline__ float bf2f(ushort_t h) {
    return __uint_as_float(((unsigned int)h) << 16);
}
__device__ __forceinline__ void gload_lds16(const void* g, void* l) {
    __builtin_amdgcn_global_load_lds(
        (const __attribute__((address_space(1))) unsigned int*)g,
        (__attribute__((address_space(3))) unsigned int*)l, 16, 0, 0);
}
__device__ __forceinline__ float wave_red(float v) {
#pragma unroll
    for (int off = 32; off > 0; off >>= 1) v += __shfl_down(v, off, 64);
    return v;
}

// ---------------- W & U -> split-bf16 transposed [n][k] planes ----------------
__global__ __launch_bounds__(256)
void convert_w(const float* __restrict__ W, const float* __restrict__ U,
               ushort_t* __restrict__ Wt, ushort_t* __restrict__ Ut) {
    const float* src = blockIdx.z ? U : W;
    ushort_t* dst = blockIdx.z ? Ut : Wt;
    __shared__ ushort_t Hs[64][65];
    __shared__ ushort_t Ls[64][65];
    const int tid = threadIdx.x;
    const int k0 = blockIdx.y * 64, n0 = blockIdx.x * 64;
    const int r = tid >> 4, c4 = (tid & 15) * 4;
#pragma unroll
    for (int i = 0; i < 4; ++i) {
        int kr = r + i * 16;
        float4 w = *(const float4*)(src + (size_t)(k0 + kr) * DD + n0 + c4);
        float wv[4] = {w.x, w.y, w.z, w.w};
#pragma unroll
        for (int j = 0; j < 4; ++j) {
            ushort_t h = f2bf(wv[j]);
            Hs[kr][c4 + j] = h;
            Ls[kr][c4 + j] = f2bf(wv[j] - bf2f(h));
        }
    }
    __syncthreads();
#pragma unroll
    for (int i = 0; i < 4; ++i) {
        int nr = r + i * 16;
        ushort4 hv = { Hs[c4+0][nr], Hs[c4+1][nr], Hs[c4+2][nr], Hs[c4+3][nr] };
        ushort4 lv = { Ls[c4+0][nr], Ls[c4+1][nr], Ls[c4+2][nr], Ls[c4+3][nr] };
        size_t base = (size_t)(n0 + nr) * KK + (size_t)(k0 + c4);
        *(ushort4*)(dst + base)        = hv;
        *(ushort4*)(dst + base + DD)   = lv;
        *(ushort4*)(dst + base + 2*DD) = hv;
    }
}

// ---------------- init: Axx = split(xin); zero scal/flags/epoch ----------------
__global__ void init_misc(const float* __restrict__ xin, ushort_t* __restrict__ Axx,
                          unsigned* __restrict__ ctrl) {
    const int i4 = blockIdx.x * 256 + threadIdx.x;   // 512 blocks
    const int idx = i4 * 4;
    const int m = idx >> 11, col = idx & 2047;
    float4 xv = ((const float4*)xin)[i4];
    float a[4] = {xv.x, xv.y, xv.z, xv.w};
    ushort_t hh[4], ll[4];
#pragma unroll
    for (int j = 0; j < 4; ++j) { hh[j] = f2bf(a[j]); ll[j] = f2bf(a[j] - bf2f(hh[j])); }
    ushort4 h = {hh[0],hh[1],hh[2],hh[3]}, l = {ll[0],ll[1],ll[2],ll[3]};
    size_t ab = (size_t)m * KK + col;
    *(ushort4*)(Axx + ab) = h; *(ushort4*)(Axx + ab + DD) = h; *(ushort4*)(Axx + ab + 2*DD) = l;
    if (blockIdx.x == 0) {
        for (int i = threadIdx.x; i < 320; i += 256) ctrl[i] = 0u;  // scal32+flags256+epoch
    }
}

// ---------------- persistent DEQ kernel ----------------
__global__ __launch_bounds__(1024, 4)
void deq_persist(const ushort_t* __restrict__ Axx, ushort_t* __restrict__ Azz,
                 const ushort_t* __restrict__ Wt, const ushort_t* __restrict__ Ut,
                 float* __restrict__ y, const float* __restrict__ bias,
                 float* __restrict__ scal, unsigned* __restrict__ flags,
                 unsigned* __restrict__ epoch, float* __restrict__ out)
{
    __shared__ ushort_t As[128 * 64];       // 16 KB
    __shared__ ushort_t Bs[128 * 64];       // 16 KB
    __shared__ float VTl[TT * DD];          // 96 KB — VTs history for this row
    __shared__ float red[16][40];
    __shared__ float coef[40];

    const int tid = threadIdx.x;
    const int bid = blockIdx.x;
    const int lane = tid & 63, w = tid >> 6;

    // GEMM job decode: ks bound to XCD (bid&7) so each XCD owns one K-slice.
    const int ksj = bid & 7;
    const int sl = bid >> 3;
    const int bn = (sl & 15) * 128;
    const int bm = (sl >> 4) * 128;

    // zero VTs LDS + Us regs
    for (int i = tid; i < TT * DD; i += 1024) VTl[i] = 0.f;
    float Usr[TT][2];
#pragma unroll
    for (int t = 0; t < TT; ++t) { Usr[t][0] = 0.f; Usr[t][1] = 0.f; }

    // staging / fragment constants
    const int grow = tid >> 3;                       // 0..127
    const int gseg = (tid & 7) ^ (grow & 7);
    const int q = lane >> 4, rl = lane & 15;
    const int waveM = w >> 2, waveN = w & 3;
    int offA[2][2], offB[2][2];
#pragma unroll
    for (int kk = 0; kk < 2; ++kk) {
        int j = kk * 4 + q;
        int m0 = waveM * 32 + rl, m1 = m0 + 16;
        int n0 = waveN * 32 + rl, n1 = n0 + 16;
        offA[kk][0] = (m0 * 8 + (j ^ (m0 & 7))) * 8;
        offA[kk][1] = (m1 * 8 + (j ^ (m1 & 7))) * 8;
        offB[kk][0] = (n0 * 8 + (j ^ (n0 & 7))) * 8;
        offB[kk][1] = (n1 * 8 + (j ^ (n1 & 7))) * 8;
    }
    ushort_t* Asp = As + tid * 8;
    ushort_t* Bsp = Bs + tid * 8;

    const int b = bid;                               // owned batch row
    const int col = tid * 2;
    const size_t rbase = (size_t)b * DD + col;

    unsigned be = 0;

    auto gbar = [&]() {
        ++be;
        __syncthreads();
        if (tid == 0) {
            __threadfence();
            __hip_atomic_store(&flags[bid], be, __ATOMIC_RELEASE, __HIP_MEMORY_SCOPE_AGENT);
        }
        if (bid == 0) {
            if (tid < NBLK) {
                while (__hip_atomic_load(&flags[tid], __ATOMIC_RELAXED, __HIP_MEMORY_SCOPE_AGENT) < be)
                    __builtin_amdgcn_s_sleep(2);
            }
            __syncthreads();
            if (tid == 0)
                __hip_atomic_store(epoch, be, __ATOMIC_RELEASE, __HIP_MEMORY_SCOPE_AGENT);
        }
        if (tid == 0) {
            while (__hip_atomic_load(epoch, __ATOMIC_RELAXED, __HIP_MEMORY_SCOPE_AGENT) < be)
                __builtin_amdgcn_s_sleep(2);
            __threadfence();
        }
        __syncthreads();
    };

    auto do_gemm = [&](const ushort_t* __restrict__ Ap, const ushort_t* __restrict__ Bp) {
        const ushort_t* Ag = Ap + (size_t)(bm + grow) * KK + ksj * 768 + gseg * 8;
        const ushort_t* Bg = Bp + (size_t)(bn + grow) * KK + ksj * 768 + gseg * 8;
        floatx4 acc00 = {0.f,0.f,0.f,0.f}, acc01 = acc00, acc10 = acc00, acc11 = acc00;
        for (int ch = 0; ch < 12; ++ch) {
            gload_lds16(Ag, Asp);
            gload_lds16(Bg, Bsp);
            Ag += 64; Bg += 64;
            __syncthreads();
#pragma unroll
            for (int kk = 0; kk < 2; ++kk) {
                short8 a0 = *(const short8*)(As + offA[kk][0]);
                short8 a1 = *(const short8*)(As + offA[kk][1]);
                short8 b0 = *(const short8*)(Bs + offB[kk][0]);
                short8 b1 = *(const short8*)(Bs + offB[kk][1]);
                acc00 = __builtin_amdgcn_mfma_f32_16x16x32_bf16(a0, b0, acc00, 0, 0, 0);
                acc01 = __builtin_amdgcn_mfma_f32_16x16x32_bf16(a0, b1, acc01, 0, 0, 0);
                acc10 = __builtin_amdgcn_mfma_f32_16x16x32_bf16(a1, b0, acc10, 0, 0, 0);
                acc11 = __builtin_amdgcn_mfma_f32_16x16x32_bf16(a1, b1, acc11, 0, 0, 0);
            }
            __syncthreads();
        }
        float* yp = y + (size_t)ksj * BD;
        const int mb = bm + waveM * 32 + q * 4;
        const int nb = bn + waveN * 32 + rl;
#pragma unroll
        for (int r = 0; r < 4; ++r) {
            yp[(size_t)(mb + r)      * DD + nb]      = acc00[r];
            yp[(size_t)(mb + r)      * DD + nb + 16] = acc01[r];
            yp[(size_t)(mb + 16 + r) * DD + nb]      = acc10[r];
            yp[(size_t)(mb + 16 + r) * DD + nb + 16] = acc11[r];
        }
    };

    // persistent per-row state (2 columns per thread)
    float c0, c1, x0v, x1v, gp0, gp1, dx0, dx1;
    float lx0, lx1, lg0, lg1, xs0, xs1, gs0, gs1, low;
    xs0 = xs1 = gs0 = gs1 = 0.f;

    // ---- phase 0: c = xin@U + b ; gx0 = tanh(c) ; x1 = gx0 ----
    do_gemm(Axx, Ut);
    gbar();
    {
        float s0 = 0.f, s1 = 0.f;
#pragma unroll
        for (int s = 0; s < 8; ++s) {
            float2 v = *(const float2*)(y + (size_t)s * BD + rbase);
            s0 += v.x; s1 += v.y;
        }
        float2 bv = *(const float2*)(bias + col);
        c0 = s0 + bv.x; c1 = s1 + bv.y;
        float g0 = tanhf(c0), g1 = tanhf(c1);
        gp0 = g0; gp1 = g1;
        dx0 = g0; dx1 = g1;
        x0v = g0; x1v = g1;
        lx0 = 0.f; lx1 = 0.f; lg0 = g0; lg1 = g1;
        ushort_t h0 = f2bf(x0v), h1 = f2bf(x1v);
        ushort_t l0 = f2bf(x0v - bf2f(h0)), l1 = f2bf(x1v - bf2f(h1));
        ushort2 hv = {h0, h1}, lv = {l0, l1};
        size_t ab = (size_t)b * KK + col;
        *(ushort2*)(Azz + ab) = hv; *(ushort2*)(Azz + ab + DD) = hv; *(ushort2*)(Azz + ab + 2*DD) = lv;
        float p = wave_red(g0 * g0 + g1 * g1);
        if (lane == 0) red[w][0] = p;
        __syncthreads();
        if (tid == 0) {
            float s = 0.f;
#pragma unroll
            for (int w2 = 0; w2 < 16; ++w2) s += red[w2][0];
            atomicAdd(&scal[0], s);
        }
    }
    gbar();
    low = sqrtf(scal[0]);

    // ---- main loop ----
    for (int k = 1; k <= TT; ++k) {
        do_gemm(Azz, Wt);
        gbar();
        {
            const int nprev = k - 1;
            float s0 = 0.f, s1 = 0.f;
#pragma unroll
            for (int s = 0; s < 8; ++s) {
                float2 v = *(const float2*)(y + (size_t)s * BD + rbase);
                s0 += v.x; s1 += v.y;
            }
            float g0 = tanhf(s0 + c0) - x0v;
            float g1 = tanhf(s1 + c1) - x1v;
            float d0 = g0 - gp0, d1 = g1 - gp1;

            // pass A: partial dots over ALL 12 slots (zero slots contribute 0)
            float pc[37];
#pragma unroll
            for (int t = 0; t < TT; ++t) {
                pc[t] = Usr[t][0] * dx0 + Usr[t][1] * dx1;
                float v0 = VTl[t * DD + col], v1 = VTl[t * DD + col + 1];
                pc[12 + t] = v0 * d0 + v1 * d1;
                pc[24 + t] = v0 * g0 + v1 * g1;
            }
            pc[36] = g0 * g0 + g1 * g1;
#pragma unroll
            for (int i = 0; i < 37; ++i) {
                float a = wave_red(pc[i]);
                if (lane == 0) red[w][i] = a;
            }
            __syncthreads();
            if (tid < 37) {
                float s = 0.f;
#pragma unroll
                for (int w2 = 0; w2 < 16; ++w2) s += red[w2][tid];
                if (tid == 36) atomicAdd(&scal[k], s);
                else coef[tid] = s;
            }
            __syncthreads();

            // pass B: vt, den, clast
            float vt0 = -dx0, vt1 = -dx1;
#pragma unroll
            for (int t = 0; t < TT; ++t) {
                float xc = coef[t];
                vt0 = fmaf(VTl[t * DD + col], xc, vt0);
                vt1 = fmaf(VTl[t * DD + col + 1], xc, vt1);
            }
            float pden = vt0 * d0 + vt1 * d1;          // denom uses UNguarded vT (ref)
            float vg0 = (vt0 != vt0) ? 0.f : vt0;
            float vg1 = (vt1 != vt1) ? 0.f : vt1;
            float pcl = vg0 * g0 + vg1 * g1;           // clast uses guarded vT
            { float a = wave_red(pden); if (lane == 0) red[w][37] = a; }
            { float a = wave_red(pcl);  if (lane == 0) red[w][38] = a; }
            __syncthreads();
            if (tid < 2) {
                float s = 0.f;
#pragma unroll
                for (int w2 = 0; w2 < 16; ++w2) s += red[w2][37 + tid];
                coef[37 + tid] = s;
            }
            __syncthreads();
            float den = coef[37], clast = coef[38];

            // write new VTs slot (runtime LDS index; own columns only)
            VTl[nprev * DD + col]     = vg0;
            VTl[nprev * DD + col + 1] = vg1;

            float un0 = dx0 + d0, un1 = dx1 + d1;
            float uo0 = g0, uo1 = g1;
#pragma unroll
            for (int t = 0; t < TT; ++t) {            // old Usr: slot nprev still zero
                un0 = fmaf(Usr[t][0], -coef[12 + t], un0);
                un1 = fmaf(Usr[t][1], -coef[12 + t], un1);
                uo0 = fmaf(Usr[t][0], -coef[24 + t], uo0);
                uo1 = fmaf(Usr[t][1], -coef[24 + t], uo1);
            }
            un0 /= den; un1 /= den;
            if (un0 != un0) un0 = 0.f;
            if (un1 != un1) un1 = 0.f;
#pragma unroll
            for (int t = 0; t < TT; ++t)
                if (t == nprev) { Usr[t][0] = un0; Usr[t][1] = un1; }
            uo0 = fmaf(un0, -clast, uo0);
            uo1 = fmaf(un1, -clast, uo1);

            xs0 = x0v; xs1 = x1v; gs0 = g0; gs1 = g1;  // save (x_k, gx_k) for argmin
            dx0 = uo0; dx1 = uo1;
            x0v += uo0; x1v += uo1;
            gp0 = g0; gp1 = g1;

            ushort_t h0 = f2bf(x0v), h1 = f2bf(x1v);
            ushort_t l0 = f2bf(x0v - bf2f(h0)), l1 = f2bf(x1v - bf2f(h1));
            ushort2 hv = {h0, h1}, lv = {l0, l1};
            size_t ab = (size_t)b * KK + col;
            *(ushort2*)(Azz + ab) = hv; *(ushort2*)(Azz + ab + DD) = hv; *(ushort2*)(Azz + ab + 2*DD) = lv;
        }
        gbar();
        float o = sqrtf(scal[k]);
        if (o < low) { low = o; lx0 = xs0; lx1 = xs1; lg0 = gs0; lg1 = gs1; }
    }

    // out = f_layer(lx) = lx + lg
    float2 ov = { lx0 + lg0, lx1 + lg1 };
    *(float2*)(out + rbase) = ov;
}

// ---------------- launch ----------------
extern "C" void kernel_launch(void* const* d_in, const int* in_sizes, int n_in,
                              void* d_out, int out_size, void* d_ws, size_t ws_size,
                              hipStream_t stream) {
    const float* xin  = (const float*)d_in[0];
    const float* W    = (const float*)d_in[2];
    const float* U    = (const float*)d_in[3];
    const float* bias = (const float*)d_in[4];
    float* out = (float*)d_out;

    float* ws = (float*)d_ws;
    float* y      = ws;                                   // 8 BD
    ushort_t* Azz = (ushort_t*)(ws + 8  * (size_t)BD);    // [256][6144] u16 = 1.5 BD
    ushort_t* Axx = (ushort_t*)(ws + 10 * (size_t)BD);    // 1.5 BD (use 9.5..11; pad to 10 for clarity? keep at 10)
    ushort_t* Wt  = (ushort_t*)(ws + 12 * (size_t)BD);    // 12 BD
    ushort_t* Ut  = (ushort_t*)(ws + 24 * (size_t)BD);    // 12 BD
    float* scal   = ws + 36 * (size_t)BD;                 // 32 floats
    unsigned* ctrl  = (unsigned*)scal;                    // scal(32) + flags(256) + epoch
    unsigned* flags = ctrl + 32;
    unsigned* epoch = flags + NBLK;

    convert_w<<<dim3(32, 32, 2), 256, 0, stream>>>(W, U, Wt, Ut);
    init_misc<<<512, 256, 0, stream>>>(xin, Axx, ctrl);
    deq_persist<<<NBLK, 1024, 0, stream>>>(Axx, Azz, Wt, Ut, y, bias, scal,
                                           flags, epoch, out);
}

// Round 6
// 528.844 us; speedup vs baseline: 2.0184x; 2.0184x over previous
//
#include <hip/hip_runtime.h>
#include <math.h>

// DEQ fixed-point via Broyden. B=256, D=2048, T=12.
// bf16 MFMA 3-term split GEMM (A=[hi|hi|lo], W=[hi;lo;hi], K=6144), split-K=4,
// double-buffered LDS staging (loads overlap MFMA).
// Broyden in Gram/coefficient space: all update vectors lie in span{gx_0..gx_k}
// (x0=0, upd0=gx0 => induction). Keep 13 gx planes + per-row state:
//   S[13][13] Gram, A[12][13] u-coeffs, B[12][13] v-coeffs, phi (upd), xi (x),
//   xisnap[13][13] (x_k coeffs per step, for final argmin output).
// Per iteration: gemm -> broyden_gram (ONE pass over gx planes, registers reused
// for dots AND x-update), scalar solve in fp64 in-block.

#define DD 2048
#define KK 6144            // 3*DD
#define BB 256
#define BD (BB * DD)
#define TT 12
#define KSLICE 1536        // KK/4
#define NITER 24           // KSLICE/64

// state layout (floats, per row, stride 1024)
#define ST_S   0           // 169
#define ST_A   169         // 12*13
#define ST_B   325         // 12*13
#define ST_PHI 481         // 13
#define ST_XI  494         // 13
#define ST_XSN 507         // 13*13
#define ST_SZ  1024

typedef unsigned short ushort_t;
typedef __attribute__((ext_vector_type(8))) short short8;
typedef __attribute__((ext_vector_type(4))) float floatx4;

__device__ __forceinline__ ushort_t f2bf(float f) {
    unsigned int u = __float_as_uint(f);
    unsigned int r = (u + 0x7FFFu + ((u >> 16) & 1u)) >> 16;
    return (ushort_t)r;
}
__device__ __forceinline__ float bf2f(ushort_t h) {
    return __uint_as_float(((unsigned int)h) << 16);
}
__device__ __forceinline__ void gload_lds16(const void* g, void* l) {
    __builtin_amdgcn_global_load_lds(
        (const __attribute__((address_space(1))) unsigned int*)g,
        (__attribute__((address_space(3))) unsigned int*)l, 16, 0, 0);
}
__device__ __forceinline__ float wave_red(float v) {
#pragma unroll
    for (int off = 32; off > 0; off >>= 1) v += __shfl_down(v, off, 64);
    return v;
}

// ---------------- W & U -> split-bf16 transposed [n][k] planes ----------------
__global__ __launch_bounds__(256)
void convert_w(const float* __restrict__ W, const float* __restrict__ U,
               ushort_t* __restrict__ Wt, ushort_t* __restrict__ Ut) {
    const float* src = blockIdx.z ? U : W;
    ushort_t* dst = blockIdx.z ? Ut : Wt;
    __shared__ ushort_t Hs[64][65];
    __shared__ ushort_t Ls[64][65];
    const int tid = threadIdx.x;
    const int k0 = blockIdx.y * 64, n0 = blockIdx.x * 64;
    const int r = tid >> 4, c4 = (tid & 15) * 4;
#pragma unroll
    for (int i = 0; i < 4; ++i) {
        int kr = r + i * 16;
        float4 w = *(const float4*)(src + (size_t)(k0 + kr) * DD + n0 + c4);
        float wv[4] = {w.x, w.y, w.z, w.w};
#pragma unroll
        for (int j = 0; j < 4; ++j) {
            ushort_t h = f2bf(wv[j]);
            Hs[kr][c4 + j] = h;
            Ls[kr][c4 + j] = f2bf(wv[j] - bf2f(h));
        }
    }
    __syncthreads();
#pragma unroll
    for (int i = 0; i < 4; ++i) {
        int nr = r + i * 16;
        ushort4 hv = { Hs[c4+0][nr], Hs[c4+1][nr], Hs[c4+2][nr], Hs[c4+3][nr] };
        ushort4 lv = { Ls[c4+0][nr], Ls[c4+1][nr], Ls[c4+2][nr], Ls[c4+3][nr] };
        size_t base = (size_t)(n0 + nr) * KK + (size_t)(k0 + c4);
        *(ushort4*)(dst + base)        = hv;
        *(ushort4*)(dst + base + DD)   = lv;
        *(ushort4*)(dst + base + 2*DD) = hv;
    }
}

// ---------------- init: Axx = split(xin); zero state+scal ----------------
__global__ void init_misc(const float* __restrict__ xin, ushort_t* __restrict__ Axx,
                          float* __restrict__ stbase) {
    const int i4 = blockIdx.x * 256 + threadIdx.x;   // 512 blocks
    const int idx = i4 * 4;
    const int m = idx >> 11, col = idx & 2047;
    float4 xv = ((const float4*)xin)[i4];
    float a[4] = {xv.x, xv.y, xv.z, xv.w};
    ushort_t hh[4], ll[4];
#pragma unroll
    for (int j = 0; j < 4; ++j) { hh[j] = f2bf(a[j]); ll[j] = f2bf(a[j] - bf2f(hh[j])); }
    ushort4 h = {hh[0],hh[1],hh[2],hh[3]}, l = {ll[0],ll[1],ll[2],ll[3]};
    size_t ab = (size_t)m * KK + col;
    *(ushort4*)(Axx + ab) = h; *(ushort4*)(Axx + ab + DD) = h; *(ushort4*)(Axx + ab + 2*DD) = l;
    // zero state (256*1024 floats = 65536 float4) + scal (32 floats = 8 float4)
    if (i4 < 65544) {
        float4 z = {0.f, 0.f, 0.f, 0.f};
        ((float4*)stbase)[i4] = z;
    }
}

// ---------------- split-bf16 MFMA GEMM, BK=64, dbuf, &7 XOR swizzle ----------------
// grid (32,16): x=n-tile, y&3=m-tile, y>>2=k-slice. 256 thr = 4 waves (2x2).
__global__ __launch_bounds__(256)
void gemm_bf16s(const ushort_t* __restrict__ A, const ushort_t* __restrict__ Bt,
                float* __restrict__ y) {
    __shared__ ushort_t As[2][64 * 64];   // 2 x 8 KB
    __shared__ ushort_t Bs[2][64 * 64];
    const int tid = threadIdx.x;
    const int lane = tid & 63, wv = tid >> 6;
    const int bn = blockIdx.x * 64;
    const int bm = (blockIdx.y & 3) * 64;
    const int ks = blockIdx.y >> 2;
    const int waveM = wv >> 1, waveN = wv & 1;

    const int srow = tid >> 3;
    const int sg = (tid & 7) ^ (srow & 7);
    const ushort_t* Ag = A  + (size_t)(bm + srow) * KK + (size_t)(ks * KSLICE + sg * 8);
    const ushort_t* Bg = Bt + (size_t)(bn + srow) * KK + (size_t)(ks * KSLICE + sg * 8);
    const size_t rowskip = (size_t)32 * KK;

    const int q = lane >> 4, rl = lane & 15;
    const int m0 = waveM * 32 + rl, m1 = m0 + 16;
    const int n0 = waveN * 32 + rl, n1 = n0 + 16;
    int offA0[2], offA1[2], offB0[2], offB1[2];
#pragma unroll
    for (int kk = 0; kk < 2; ++kk) {
        int j = kk * 4 + q;
        offA0[kk] = (m0 * 8 + (j ^ (m0 & 7))) * 8;
        offA1[kk] = (m1 * 8 + (j ^ (m1 & 7))) * 8;
        offB0[kk] = (n0 * 8 + (j ^ (n0 & 7))) * 8;
        offB1[kk] = (n1 * 8 + (j ^ (n1 & 7))) * 8;
    }

    floatx4 acc00 = {0.f,0.f,0.f,0.f}, acc01 = acc00, acc10 = acc00, acc11 = acc00;

    // preload chunk 0 into buffer 0
    gload_lds16(Ag, As[0] + tid * 8);
    gload_lds16(Ag + rowskip, As[0] + (256 + tid) * 8);
    gload_lds16(Bg, Bs[0] + tid * 8);
    gload_lds16(Bg + rowskip, Bs[0] + (256 + tid) * 8);
    Ag += 64; Bg += 64;
    __syncthreads();

    for (int it = 0; it < NITER; ++it) {
        const int cur = it & 1, nxt = cur ^ 1;
        if (it + 1 < NITER) {   // issue next chunk's loads BEFORE mfma (overlap)
            gload_lds16(Ag, As[nxt] + tid * 8);
            gload_lds16(Ag + rowskip, As[nxt] + (256 + tid) * 8);
            gload_lds16(Bg, Bs[nxt] + tid * 8);
            gload_lds16(Bg + rowskip, Bs[nxt] + (256 + tid) * 8);
            Ag += 64; Bg += 64;
        }
        const ushort_t* Ab = As[cur];
        const ushort_t* Bb = Bs[cur];
#pragma unroll
        for (int kk = 0; kk < 2; ++kk) {
            short8 a0 = *(const short8*)(Ab + offA0[kk]);
            short8 a1 = *(const short8*)(Ab + offA1[kk]);
            short8 b0 = *(const short8*)(Bb + offB0[kk]);
            short8 b1 = *(const short8*)(Bb + offB1[kk]);
            acc00 = __builtin_amdgcn_mfma_f32_16x16x32_bf16(a0, b0, acc00, 0, 0, 0);
            acc01 = __builtin_amdgcn_mfma_f32_16x16x32_bf16(a0, b1, acc01, 0, 0, 0);
            acc10 = __builtin_amdgcn_mfma_f32_16x16x32_bf16(a1, b0, acc10, 0, 0, 0);
            acc11 = __builtin_amdgcn_mfma_f32_16x16x32_bf16(a1, b1, acc11, 0, 0, 0);
        }
        __syncthreads();
    }

    float* yp = y + (size_t)ks * BD;
    const int mb = bm + waveM * 32 + q * 4;
    const int nb = bn + waveN * 32 + rl;
#pragma unroll
    for (int r = 0; r < 4; ++r) {
        yp[(size_t)(mb + r)      * DD + nb]      = acc00[r];
        yp[(size_t)(mb + r)      * DD + nb + 16] = acc01[r];
        yp[(size_t)(mb + 16 + r) * DD + nb]      = acc10[r];
        yp[(size_t)(mb + 16 + r) * DD + nb + 16] = acc11[r];
    }
}

// ---------------- step 0: c, g0 = tanh(c), Azz = split(g0), state init ----------------
__global__ __launch_bounds__(512)
void epi0(const float* __restrict__ y, const float* __restrict__ bias,
          float* __restrict__ c, float* __restrict__ gxp,
          ushort_t* __restrict__ Azz, float* __restrict__ state,
          float* __restrict__ scal) {
    __shared__ float red[8];
    const int tid = threadIdx.x;
    const int b = blockIdx.x;
    const int col = tid * 4;
    const size_t base = (size_t)b * DD + col;

    float4 s0 = *(const float4*)(y + base);
    float4 s1 = *(const float4*)(y + (size_t)BD + base);
    float4 s2 = *(const float4*)(y + 2 * (size_t)BD + base);
    float4 s3 = *(const float4*)(y + 3 * (size_t)BD + base);
    float4 bv = *(const float4*)(bias + col);
    float4 cc = { s0.x+s1.x+s2.x+s3.x+bv.x, s0.y+s1.y+s2.y+s3.y+bv.y,
                  s0.z+s1.z+s2.z+s3.z+bv.z, s0.w+s1.w+s2.w+s3.w+bv.w };
    *(float4*)(c + base) = cc;
    float4 g = { tanhf(cc.x), tanhf(cc.y), tanhf(cc.z), tanhf(cc.w) };
    *(float4*)(gxp + base) = g;                     // g_0 plane

    // Azz = split(x_1) = split(g_0)
    float a[4] = {g.x, g.y, g.z, g.w};
    ushort_t hh[4], ll[4];
#pragma unroll
    for (int j = 0; j < 4; ++j) { hh[j] = f2bf(a[j]); ll[j] = f2bf(a[j] - bf2f(hh[j])); }
    ushort4 h = {hh[0],hh[1],hh[2],hh[3]}, l = {ll[0],ll[1],ll[2],ll[3]};
    size_t ab = (size_t)b * KK + col;
    *(ushort4*)(Azz + ab) = h; *(ushort4*)(Azz + ab + DD) = h; *(ushort4*)(Azz + ab + 2*DD) = l;

    float pd = g.x*g.x + g.y*g.y + g.z*g.z + g.w*g.w;
    pd = wave_red(pd);
    if ((tid & 63) == 0) red[tid >> 6] = pd;
    __syncthreads();
    if (tid == 0) {
        float t = 0.f;
#pragma unroll
        for (int w2 = 0; w2 < 8; ++w2) t += red[w2];
        float* stb = state + (size_t)b * ST_SZ;
        stb[ST_S + 0]   = t;      // S[0][0]
        stb[ST_PHI + 0] = 1.f;    // upd_0 = g_0
        stb[ST_XI + 0]  = 1.f;    // x_1 = g_0
        atomicAdd(&scal[0], t);
    }
}

// ---------------- Gram-space Broyden: one pass over gx planes ----------------
// Block b owns row b. 512 thr x 4 cols. k in [1..12], p = k-1 new slot index.
__global__ __launch_bounds__(512)
void broyden_gram(const float* __restrict__ y, const float* __restrict__ c,
                  float* __restrict__ gxp, ushort_t* __restrict__ Azz,
                  float* __restrict__ state, float* __restrict__ scal, int k)
{
    __shared__ float red[8][16];
    __shared__ float dots[14];
    __shared__ float Sl[169], Al[156], Bl[156], PHl[13], XIl[13];
    __shared__ float newA[14], newB[14], nphi[14];
    __shared__ double dyv[13], dxtu[12], dvdg[12], dcgx[13], dden[1];
    const int tid = threadIdx.x;
    const int lane = tid & 63, w = tid >> 6;
    const int b = blockIdx.x;
    const int p = k - 1;
    float* stb = state + (size_t)b * ST_SZ;

    // preload coefficient state into LDS
    for (int i = tid; i < 169; i += 512) Sl[i] = stb[ST_S + i];
    for (int i = tid; i < 156; i += 512) { Al[i] = stb[ST_A + i]; Bl[i] = stb[ST_B + i]; }
    if (tid < 13) { PHl[tid] = stb[ST_PHI + tid]; XIl[tid] = stb[ST_XI + tid]; }

    const int col = tid * 4;
    const size_t base = (size_t)b * DD + col;
    float4 s0 = *(const float4*)(y + base);
    float4 s1 = *(const float4*)(y + (size_t)BD + base);
    float4 s2 = *(const float4*)(y + 2 * (size_t)BD + base);
    float4 s3 = *(const float4*)(y + 3 * (size_t)BD + base);
    float4 cv = *(const float4*)(c + base);
    float4 pre = { s0.x+s1.x+s2.x+s3.x+cv.x, s0.y+s1.y+s2.y+s3.y+cv.y,
                   s0.z+s1.z+s2.z+s3.z+cv.z, s0.w+s1.w+s2.w+s3.w+cv.w };

    float4 G[12];
#pragma unroll
    for (int j = 0; j < 12; ++j)
        if (j < k) G[j] = *(const float4*)(gxp + (size_t)j * BD + base);

    __syncthreads();   // XIl/state ready

    // x_k = sum_j xi[j] g_j
    float4 x = {0.f, 0.f, 0.f, 0.f};
#pragma unroll
    for (int j = 0; j < 12; ++j)
        if (j < k) {
            float xc = XIl[j];
            x.x = fmaf(xc, G[j].x, x.x); x.y = fmaf(xc, G[j].y, x.y);
            x.z = fmaf(xc, G[j].z, x.z); x.w = fmaf(xc, G[j].w, x.w);
        }
    float4 gk = { tanhf(pre.x) - x.x, tanhf(pre.y) - x.y,
                  tanhf(pre.z) - x.z, tanhf(pre.w) - x.w };

    // dots s[j] = g_j . g_k (j<k) and s[k] = g_k . g_k
#pragma unroll
    for (int j = 0; j < 12; ++j)
        if (j < k) {
            float pd = G[j].x*gk.x + G[j].y*gk.y + G[j].z*gk.z + G[j].w*gk.w;
            pd = wave_red(pd);
            if (lane == 0) red[w][j] = pd;
        }
    {
        float pdk = gk.x*gk.x + gk.y*gk.y + gk.z*gk.z + gk.w*gk.w;
        pdk = wave_red(pdk);
        if (lane == 0) red[w][k] = pdk;
    }
    __syncthreads();
    if (tid <= k) {
        float s = 0.f;
#pragma unroll
        for (int w2 = 0; w2 < 8; ++w2) s += red[w2][tid];
        dots[tid] = s;
        if (tid == k) atomicAdd(&scal[k], s);
    }
    __syncthreads();

    // ---- scalar solve (fp64) ----
    // yv[i] = sum_j S[i][j] phi[j]   (i<k)
    if (tid < k) {
        double s = 0.0;
        for (int j = 0; j < k; ++j) s += (double)Sl[tid*13 + j] * (double)PHl[j];
        dyv[tid] = s;
    }
    __syncthreads();
    // xtu[t] = A_t . yv ; vdg[t] = B_t . (s - S[:,k-1])   (t<p)
    if (tid < p) {
        double sx = 0.0, sv = 0.0;
        for (int j = 0; j < k; ++j) {
            sx += (double)Al[tid*13 + j] * dyv[j];
            sv += (double)Bl[tid*13 + j] * ((double)dots[j] - (double)Sl[j*13 + (k-1)]);
        }
        dxtu[tid] = sx; dvdg[tid] = sv;
    }
    __syncthreads();
    // B_p[j] = -phi[j] + sum_t xtu[t] B_t[j]   (j<k)
    if (tid < k) {
        double s = -(double)PHl[tid];
        for (int t = 0; t < p; ++t) s += dxtu[t] * (double)Bl[t*13 + tid];
        newB[tid] = (float)s;
    }
    __syncthreads();
    // den = B_p . (s - S[:,k-1])
    if (tid == 0) {
        double s = 0.0;
        for (int j = 0; j < k; ++j)
            s += (double)newB[j] * ((double)dots[j] - (double)Sl[j*13 + (k-1)]);
        dden[0] = s;
    }
    __syncthreads();
    // A_p[j] = (phi[j] + d_{jk} - d_{j,k-1} - sum_t vdg[t] A_t[j]) / den   (j<=k)
    // cgx[t] = B_t . s (t<p, lanes 32..), cgx[p] = B_p . s (lane 63)
    if (tid <= k) {
        double s = (double)((tid < 13) ? PHl[tid] : 0.f);
        if (tid == k)     s += 1.0;
        if (tid == k - 1) s -= 1.0;
        for (int t = 0; t < p; ++t) s -= dvdg[t] * (double)Al[t*13 + tid];
        newA[tid] = (float)(s / dden[0]);
    }
    if (tid >= 32 && tid < 32 + p) {
        int t = tid - 32;
        double s = 0.0;
        for (int j = 0; j < k; ++j) s += (double)Bl[t*13 + j] * (double)dots[j];
        dcgx[t] = s;
    }
    if (tid == 63) {
        double s = 0.0;
        for (int j = 0; j < k; ++j) s += (double)newB[j] * (double)dots[j];
        dcgx[p] = s;
    }
    __syncthreads();
    // phi'[j] = d_{jk} - sum_{t<p} cgx[t] A_t[j] - cgx[p] A_p[j]   (j<=k)
    if (tid <= k) {
        double s = (tid == k) ? 1.0 : 0.0;
        for (int t = 0; t < p; ++t) s -= dcgx[t] * (double)Al[t*13 + tid];
        s -= dcgx[p] * (double)newA[tid];
        nphi[tid] = (float)s;
    }
    __syncthreads();

    // state write-back
    if (tid <= k) {
        stb[ST_S + k*13 + tid] = dots[tid];
        stb[ST_S + tid*13 + k] = dots[tid];
        stb[ST_A + p*13 + tid] = newA[tid];
        stb[ST_PHI + tid] = nphi[tid];
        float xi_old = (tid < 13) ? XIl[tid] : 0.f;
        stb[ST_XI + tid] = xi_old + nphi[tid];
    }
    if (tid < k) stb[ST_B + p*13 + tid] = newB[tid];
    if (tid < 13) stb[ST_XSN + k*13 + tid] = XIl[tid];   // coeffs of x_k (candidate)

    // x_{k+1} = x_k + sum_{j<k} phi'[j] g_j + phi'[k] g_k   (registers reused!)
    float4 xn = x;
#pragma unroll
    for (int j = 0; j < 12; ++j)
        if (j < k) {
            float fc = nphi[j];
            xn.x = fmaf(fc, G[j].x, xn.x); xn.y = fmaf(fc, G[j].y, xn.y);
            xn.z = fmaf(fc, G[j].z, xn.z); xn.w = fmaf(fc, G[j].w, xn.w);
        }
    {
        float fk = nphi[k];
        xn.x = fmaf(fk, gk.x, xn.x); xn.y = fmaf(fk, gk.y, xn.y);
        xn.z = fmaf(fk, gk.z, xn.z); xn.w = fmaf(fk, gk.w, xn.w);
    }

    *(float4*)(gxp + (size_t)k * BD + base) = gk;     // store g_k plane

    float a[4] = {xn.x, xn.y, xn.z, xn.w};
    ushort_t hh[4], ll[4];
#pragma unroll
    for (int j = 0; j < 4; ++j) { hh[j] = f2bf(a[j]); ll[j] = f2bf(a[j] - bf2f(hh[j])); }
    ushort4 h = {hh[0],hh[1],hh[2],hh[3]}, l = {ll[0],ll[1],ll[2],ll[3]};
    size_t ab = (size_t)b * KK + col;
    *(ushort4*)(Azz + ab) = h; *(ushort4*)(Azz + ab + DD) = h; *(ushort4*)(Azz + ab + 2*DD) = l;
}

// ---------------- final: argmin obj; out = x_bk + g_bk ----------------
__global__ __launch_bounds__(256)
void final_out(const float* __restrict__ gxp, const float* __restrict__ state,
               const float* __restrict__ scal, float* __restrict__ out) {
    const int i4 = blockIdx.x * 256 + threadIdx.x;
    float best = scal[0];
    int bk = 0;
#pragma unroll
    for (int k = 1; k <= TT; ++k) {              // squared norms; sqrt monotone
        float o = scal[k];
        if (o < best) { best = o; bk = k; }
    }
    const size_t idx = (size_t)i4 * 4;
    const int m = (int)(idx >> 11);
    const float* cf = state + (size_t)m * ST_SZ + ST_XSN + bk * 13;
    float4 r = *(const float4*)(gxp + (size_t)bk * BD + idx);
    for (int j = 0; j < bk; ++j) {
        float c1 = cf[j];
        float4 g = *(const float4*)(gxp + (size_t)j * BD + idx);
        r.x = fmaf(c1, g.x, r.x); r.y = fmaf(c1, g.y, r.y);
        r.z = fmaf(c1, g.z, r.z); r.w = fmaf(c1, g.w, r.w);
    }
    ((float4*)out)[i4] = r;
}

// ---------------- launch ----------------
extern "C" void kernel_launch(void* const* d_in, const int* in_sizes, int n_in,
                              void* d_out, int out_size, void* d_ws, size_t ws_size,
                              hipStream_t stream) {
    const float* xin  = (const float*)d_in[0];
    const float* W    = (const float*)d_in[2];
    const float* U    = (const float*)d_in[3];
    const float* bias = (const float*)d_in[4];
    float* out = (float*)d_out;

    float* ws = (float*)d_ws;
    float* c      = ws;                                   // 1 BD
    float* y      = ws + 1 * (size_t)BD;                  // 4 BD
    float* gxp    = ws + 5 * (size_t)BD;                  // 13 BD (g_0..g_12)
    ushort_t* Axx = (ushort_t*)(ws + 18 * (size_t)BD);    // 1.5 BD
    ushort_t* Azz = (ushort_t*)(ws + 20 * (size_t)BD);    // 1.5 BD
    ushort_t* Wt  = (ushort_t*)(ws + 22 * (size_t)BD);    // 12 BD
    ushort_t* Ut  = (ushort_t*)(ws + 34 * (size_t)BD);    // 12 BD
    float* state  = ws + 46 * (size_t)BD;                 // 256*1024 = 0.5 BD
    float* scal   = state + (size_t)BB * ST_SZ;           // 32 floats (contiguous after state)

    convert_w<<<dim3(32, 32, 2), 256, 0, stream>>>(W, U, Wt, Ut);
    init_misc<<<512, 256, 0, stream>>>(xin, Axx, state);  // zeroes state+scal too

    dim3 gg(32, 16);
    gemm_bf16s<<<gg, 256, 0, stream>>>(Axx, Ut, y);
    epi0<<<BB, 512, 0, stream>>>(y, bias, c, gxp, Azz, state, scal);

    for (int k = 1; k <= TT; ++k) {
        gemm_bf16s<<<gg, 256, 0, stream>>>(Azz, Wt, y);
        broyden_gram<<<BB, 512, 0, stream>>>(y, c, gxp, Azz, state, scal, k);
    }

    final_out<<<512, 256, 0, stream>>>(gxp, state, scal, out);
}

// Round 7
// 481.718 us; speedup vs baseline: 2.2159x; 1.0978x over previous
//
#include <hip/hip_runtime.h>
#include <math.h>

// DEQ fixed-point via Broyden. B=256, D=2048, T=12.
// bf16 MFMA 3-term split GEMM (A=[hi|hi|lo], W=[hi;lo;hi], K=6144).
// R7: M-resident GEMM tiling — mtile=256 (all of M in LDS), ntile=64,
// split-K=8 -> 256 blocks x 512 thr. staged traffic 192->126 MB/GEMM,
// A-panel shared by all 32 n-blocks of a K-slice (L2-friendly).
// Broyden in Gram/coefficient space (R6, verified): 13 gx planes + per-row
// 13-dim coeff state; scalar solve fp64 in-block.

#define DD 2048
#define KK 6144            // 3*DD
#define BB 256
#define BD (BB * DD)
#define TT 12
#define NKS 8              // split-K slices
#define KS 768             // KK/NKS
#define NITER 12           // KS/64

// state layout (floats, per row, stride 1024)
#define ST_S   0           // 169
#define ST_A   169         // 12*13
#define ST_B   325         // 12*13
#define ST_PHI 481         // 13
#define ST_XI  494         // 13
#define ST_XSN 507         // 13*13
#define ST_SZ  1024

typedef unsigned short ushort_t;
typedef __attribute__((ext_vector_type(8))) short short8;
typedef __attribute__((ext_vector_type(4))) float floatx4;

__device__ __forceinline__ ushort_t f2bf(float f) {
    unsigned int u = __float_as_uint(f);
    unsigned int r = (u + 0x7FFFu + ((u >> 16) & 1u)) >> 16;
    return (ushort_t)r;
}
__device__ __forceinline__ float bf2f(ushort_t h) {
    return __uint_as_float(((unsigned int)h) << 16);
}
__device__ __forceinline__ void gload_lds16(const void* g, void* l) {
    __builtin_amdgcn_global_load_lds(
        (const __attribute__((address_space(1))) unsigned int*)g,
        (__attribute__((address_space(3))) unsigned int*)l, 16, 0, 0);
}
__device__ __forceinline__ float wave_red(float v) {
#pragma unroll
    for (int off = 32; off > 0; off >>= 1) v += __shfl_down(v, off, 64);
    return v;
}

// ---------------- W & U -> split-bf16 transposed [n][k] planes ----------------
__global__ __launch_bounds__(256)
void convert_w(const float* __restrict__ W, const float* __restrict__ U,
               ushort_t* __restrict__ Wt, ushort_t* __restrict__ Ut) {
    const float* src = blockIdx.z ? U : W;
    ushort_t* dst = blockIdx.z ? Ut : Wt;
    __shared__ ushort_t Hs[64][65];
    __shared__ ushort_t Ls[64][65];
    const int tid = threadIdx.x;
    const int k0 = blockIdx.y * 64, n0 = blockIdx.x * 64;
    const int r = tid >> 4, c4 = (tid & 15) * 4;
#pragma unroll
    for (int i = 0; i < 4; ++i) {
        int kr = r + i * 16;
        float4 w = *(const float4*)(src + (size_t)(k0 + kr) * DD + n0 + c4);
        float wv[4] = {w.x, w.y, w.z, w.w};
#pragma unroll
        for (int j = 0; j < 4; ++j) {
            ushort_t h = f2bf(wv[j]);
            Hs[kr][c4 + j] = h;
            Ls[kr][c4 + j] = f2bf(wv[j] - bf2f(h));
        }
    }
    __syncthreads();
#pragma unroll
    for (int i = 0; i < 4; ++i) {
        int nr = r + i * 16;
        ushort4 hv = { Hs[c4+0][nr], Hs[c4+1][nr], Hs[c4+2][nr], Hs[c4+3][nr] };
        ushort4 lv = { Ls[c4+0][nr], Ls[c4+1][nr], Ls[c4+2][nr], Ls[c4+3][nr] };
        size_t base = (size_t)(n0 + nr) * KK + (size_t)(k0 + c4);
        *(ushort4*)(dst + base)        = hv;
        *(ushort4*)(dst + base + DD)   = lv;
        *(ushort4*)(dst + base + 2*DD) = hv;
    }
}

// ---------------- init: Axx = split(xin); zero state+scal ----------------
__global__ void init_misc(const float* __restrict__ xin, ushort_t* __restrict__ Axx,
                          float* __restrict__ stbase) {
    const int i4 = blockIdx.x * 256 + threadIdx.x;   // 512 blocks
    const int idx = i4 * 4;
    const int m = idx >> 11, col = idx & 2047;
    float4 xv = ((const float4*)xin)[i4];
    float a[4] = {xv.x, xv.y, xv.z, xv.w};
    ushort_t hh[4], ll[4];
#pragma unroll
    for (int j = 0; j < 4; ++j) { hh[j] = f2bf(a[j]); ll[j] = f2bf(a[j] - bf2f(hh[j])); }
    ushort4 h = {hh[0],hh[1],hh[2],hh[3]}, l = {ll[0],ll[1],ll[2],ll[3]};
    size_t ab = (size_t)m * KK + col;
    *(ushort4*)(Axx + ab) = h; *(ushort4*)(Axx + ab + DD) = h; *(ushort4*)(Axx + ab + 2*DD) = l;
    if (i4 < 65544) {            // state 256*1024 floats + scal 32
        float4 z = {0.f, 0.f, 0.f, 0.f};
        ((float4*)stbase)[i4] = z;
    }
}

// ---------------- M-resident split-bf16 MFMA GEMM ----------------
// grid (32, 8): x = n-tile (64 wide), y = k-slice (768). 512 thr = 8 waves,
// wave-tile 64x32 (waveM = w>>1 in 0..3, waveN = w&1).
// A chunk 256x64 (32 KB), B chunk 64x64 (8 KB), double-buffered.
__global__ __launch_bounds__(512)
void gemm_bf16s(const ushort_t* __restrict__ A, const ushort_t* __restrict__ Bt,
                float* __restrict__ y) {
    __shared__ ushort_t As[2][256 * 64];   // 2 x 32 KB
    __shared__ ushort_t Bs[2][64 * 64];    // 2 x 8 KB
    const int tid = threadIdx.x;
    const int lane = tid & 63, w = tid >> 6;
    const int bn = blockIdx.x * 64;
    const int ks = blockIdx.y;
    const int waveM = w >> 1, waveN = w & 1;

    // staging: thread t covers granule (row = t>>3 [+64*i for A], g) where
    // g = (t&7) ^ ((t>>3)&7)  (invariant under row += 64). LDS slot = t + 512*i.
    const int srow = tid >> 3;
    const int sg = (tid & 7) ^ (srow & 7);
    const ushort_t* Ag = A  + (size_t)srow * KK + ks * KS + sg * 8;
    const ushort_t* Bg = Bt + (size_t)(bn + srow) * KK + ks * KS + sg * 8;
    const size_t rs64 = (size_t)64 * KK;

    // fragment read offsets: logical granule (m, j=kk*4+q) at slot m*8 + (j^(m&7))
    const int q = lane >> 4, rl = lane & 15;
    int offA[2][4], offB[2][2];
#pragma unroll
    for (int kk = 0; kk < 2; ++kk) {
        int j = kk * 4 + q;
#pragma unroll
        for (int mi = 0; mi < 4; ++mi) {
            int m = waveM * 64 + mi * 16 + rl;
            offA[kk][mi] = (m * 8 + (j ^ (m & 7))) * 8;
        }
#pragma unroll
        for (int ni = 0; ni < 2; ++ni) {
            int n = waveN * 32 + ni * 16 + rl;
            offB[kk][ni] = (n * 8 + (j ^ (n & 7))) * 8;
        }
    }

    floatx4 acc[4][2];
#pragma unroll
    for (int mi = 0; mi < 4; ++mi)
#pragma unroll
        for (int ni = 0; ni < 2; ++ni) acc[mi][ni] = (floatx4){0.f,0.f,0.f,0.f};

    // preload chunk 0
    gload_lds16(Ag,            As[0] + tid * 8);
    gload_lds16(Ag + rs64,     As[0] + (512 + tid) * 8);
    gload_lds16(Ag + 2 * rs64, As[0] + (1024 + tid) * 8);
    gload_lds16(Ag + 3 * rs64, As[0] + (1536 + tid) * 8);
    gload_lds16(Bg,            Bs[0] + tid * 8);
    Ag += 64; Bg += 64;
    __syncthreads();

    for (int it = 0; it < NITER; ++it) {
        const int cur = it & 1, nxt = cur ^ 1;
        if (it + 1 < NITER) {    // issue next loads before MFMA (overlap)
            gload_lds16(Ag,            As[nxt] + tid * 8);
            gload_lds16(Ag + rs64,     As[nxt] + (512 + tid) * 8);
            gload_lds16(Ag + 2 * rs64, As[nxt] + (1024 + tid) * 8);
            gload_lds16(Ag + 3 * rs64, As[nxt] + (1536 + tid) * 8);
            gload_lds16(Bg,            Bs[nxt] + tid * 8);
            Ag += 64; Bg += 64;
        }
        const ushort_t* Ab = As[cur];
        const ushort_t* Bb = Bs[cur];
#pragma unroll
        for (int kk = 0; kk < 2; ++kk) {
            short8 b0 = *(const short8*)(Bb + offB[kk][0]);
            short8 b1 = *(const short8*)(Bb + offB[kk][1]);
#pragma unroll
            for (int mi = 0; mi < 4; ++mi) {
                short8 a = *(const short8*)(Ab + offA[kk][mi]);
                acc[mi][0] = __builtin_amdgcn_mfma_f32_16x16x32_bf16(a, b0, acc[mi][0], 0, 0, 0);
                acc[mi][1] = __builtin_amdgcn_mfma_f32_16x16x32_bf16(a, b1, acc[mi][1], 0, 0, 0);
            }
        }
        __syncthreads();
    }

    // C/D: col = lane&15, row = (lane>>4)*4 + reg
    float* yp = y + (size_t)ks * BD;
    const int mb = waveM * 64 + q * 4;
    const int nb = bn + waveN * 32 + rl;
#pragma unroll
    for (int mi = 0; mi < 4; ++mi)
#pragma unroll
        for (int r = 0; r < 4; ++r) {
            yp[(size_t)(mb + mi * 16 + r) * DD + nb]      = acc[mi][0][r];
            yp[(size_t)(mb + mi * 16 + r) * DD + nb + 16] = acc[mi][1][r];
        }
}

// ---------------- step 0: c, g0 = tanh(c), Azz = split(g0), state init ----------------
__global__ __launch_bounds__(512)
void epi0(const float* __restrict__ y, const float* __restrict__ bias,
          float* __restrict__ c, float* __restrict__ gxp,
          ushort_t* __restrict__ Azz, float* __restrict__ state,
          float* __restrict__ scal) {
    __shared__ float red[8];
    const int tid = threadIdx.x;
    const int b = blockIdx.x;
    const int col = tid * 4;
    const size_t base = (size_t)b * DD + col;

    float4 cc = *(const float4*)(bias + col);
#pragma unroll
    for (int s = 0; s < NKS; ++s) {
        float4 v = *(const float4*)(y + (size_t)s * BD + base);
        cc.x += v.x; cc.y += v.y; cc.z += v.z; cc.w += v.w;
    }
    *(float4*)(c + base) = cc;
    float4 g = { tanhf(cc.x), tanhf(cc.y), tanhf(cc.z), tanhf(cc.w) };
    *(float4*)(gxp + base) = g;                     // g_0 plane

    float a[4] = {g.x, g.y, g.z, g.w};
    ushort_t hh[4], ll[4];
#pragma unroll
    for (int j = 0; j < 4; ++j) { hh[j] = f2bf(a[j]); ll[j] = f2bf(a[j] - bf2f(hh[j])); }
    ushort4 h = {hh[0],hh[1],hh[2],hh[3]}, l = {ll[0],ll[1],ll[2],ll[3]};
    size_t ab = (size_t)b * KK + col;
    *(ushort4*)(Azz + ab) = h; *(ushort4*)(Azz + ab + DD) = h; *(ushort4*)(Azz + ab + 2*DD) = l;

    float pd = g.x*g.x + g.y*g.y + g.z*g.z + g.w*g.w;
    pd = wave_red(pd);
    if ((tid & 63) == 0) red[tid >> 6] = pd;
    __syncthreads();
    if (tid == 0) {
        float t = 0.f;
#pragma unroll
        for (int w2 = 0; w2 < 8; ++w2) t += red[w2];
        float* stb = state + (size_t)b * ST_SZ;
        stb[ST_S + 0]   = t;
        stb[ST_PHI + 0] = 1.f;
        stb[ST_XI + 0]  = 1.f;
        atomicAdd(&scal[0], t);
    }
}

// ---------------- Gram-space Broyden: one pass over gx planes ----------------
__global__ __launch_bounds__(512)
void broyden_gram(const float* __restrict__ y, const float* __restrict__ c,
                  float* __restrict__ gxp, ushort_t* __restrict__ Azz,
                  float* __restrict__ state, float* __restrict__ scal, int k)
{
    __shared__ float red[8][16];
    __shared__ float dots[14];
    __shared__ float Sl[169], Al[156], Bl[156], PHl[13], XIl[13];
    __shared__ float newA[14], newB[14], nphi[14];
    __shared__ double dyv[13], dxtu[12], dvdg[12], dcgx[13], dden[1];
    const int tid = threadIdx.x;
    const int lane = tid & 63, w = tid >> 6;
    const int b = blockIdx.x;
    const int p = k - 1;
    float* stb = state + (size_t)b * ST_SZ;

    for (int i = tid; i < 169; i += 512) Sl[i] = stb[ST_S + i];
    for (int i = tid; i < 156; i += 512) { Al[i] = stb[ST_A + i]; Bl[i] = stb[ST_B + i]; }
    if (tid < 13) { PHl[tid] = stb[ST_PHI + tid]; XIl[tid] = stb[ST_XI + tid]; }

    const int col = tid * 4;
    const size_t base = (size_t)b * DD + col;
    float4 pre = *(const float4*)(c + base);
#pragma unroll
    for (int s = 0; s < NKS; ++s) {
        float4 v = *(const float4*)(y + (size_t)s * BD + base);
        pre.x += v.x; pre.y += v.y; pre.z += v.z; pre.w += v.w;
    }

    float4 G[12];
#pragma unroll
    for (int j = 0; j < 12; ++j)
        if (j < k) G[j] = *(const float4*)(gxp + (size_t)j * BD + base);

    __syncthreads();

    float4 x = {0.f, 0.f, 0.f, 0.f};
#pragma unroll
    for (int j = 0; j < 12; ++j)
        if (j < k) {
            float xc = XIl[j];
            x.x = fmaf(xc, G[j].x, x.x); x.y = fmaf(xc, G[j].y, x.y);
            x.z = fmaf(xc, G[j].z, x.z); x.w = fmaf(xc, G[j].w, x.w);
        }
    float4 gk = { tanhf(pre.x) - x.x, tanhf(pre.y) - x.y,
                  tanhf(pre.z) - x.z, tanhf(pre.w) - x.w };

#pragma unroll
    for (int j = 0; j < 12; ++j)
        if (j < k) {
            float pd = G[j].x*gk.x + G[j].y*gk.y + G[j].z*gk.z + G[j].w*gk.w;
            pd = wave_red(pd);
            if (lane == 0) red[w][j] = pd;
        }
    {
        float pdk = gk.x*gk.x + gk.y*gk.y + gk.z*gk.z + gk.w*gk.w;
        pdk = wave_red(pdk);
        if (lane == 0) red[w][k] = pdk;
    }
    __syncthreads();
    if (tid <= k) {
        float s = 0.f;
#pragma unroll
        for (int w2 = 0; w2 < 8; ++w2) s += red[w2][tid];
        dots[tid] = s;
        if (tid == k) atomicAdd(&scal[k], s);
    }
    __syncthreads();

    // ---- scalar solve (fp64) ----
    if (tid < k) {
        double s = 0.0;
        for (int j = 0; j < k; ++j) s += (double)Sl[tid*13 + j] * (double)PHl[j];
        dyv[tid] = s;
    }
    __syncthreads();
    if (tid < p) {
        double sx = 0.0, sv = 0.0;
        for (int j = 0; j < k; ++j) {
            sx += (double)Al[tid*13 + j] * dyv[j];
            sv += (double)Bl[tid*13 + j] * ((double)dots[j] - (double)Sl[j*13 + (k-1)]);
        }
        dxtu[tid] = sx; dvdg[tid] = sv;
    }
    __syncthreads();
    if (tid < k) {
        double s = -(double)PHl[tid];
        for (int t = 0; t < p; ++t) s += dxtu[t] * (double)Bl[t*13 + tid];
        newB[tid] = (float)s;
    }
    __syncthreads();
    if (tid == 0) {
        double s = 0.0;
        for (int j = 0; j < k; ++j)
            s += (double)newB[j] * ((double)dots[j] - (double)Sl[j*13 + (k-1)]);
        dden[0] = s;
    }
    __syncthreads();
    if (tid <= k) {
        double s = (double)((tid < 13) ? PHl[tid] : 0.f);
        if (tid == k)     s += 1.0;
        if (tid == k - 1) s -= 1.0;
        for (int t = 0; t < p; ++t) s -= dvdg[t] * (double)Al[t*13 + tid];
        newA[tid] = (float)(s / dden[0]);
    }
    if (tid >= 32 && tid < 32 + p) {
        int t = tid - 32;
        double s = 0.0;
        for (int j = 0; j < k; ++j) s += (double)Bl[t*13 + j] * (double)dots[j];
        dcgx[t] = s;
    }
    if (tid == 63) {
        double s = 0.0;
        for (int j = 0; j < k; ++j) s += (double)newB[j] * (double)dots[j];
        dcgx[p] = s;
    }
    __syncthreads();
    if (tid <= k) {
        double s = (tid == k) ? 1.0 : 0.0;
        for (int t = 0; t < p; ++t) s -= dcgx[t] * (double)Al[t*13 + tid];
        s -= dcgx[p] * (double)newA[tid];
        nphi[tid] = (float)s;
    }
    __syncthreads();

    if (tid <= k) {
        stb[ST_S + k*13 + tid] = dots[tid];
        stb[ST_S + tid*13 + k] = dots[tid];
        stb[ST_A + p*13 + tid] = newA[tid];
        stb[ST_PHI + tid] = nphi[tid];
        float xi_old = (tid < 13) ? XIl[tid] : 0.f;
        stb[ST_XI + tid] = xi_old + nphi[tid];
    }
    if (tid < k) stb[ST_B + p*13 + tid] = newB[tid];
    if (tid < 13) stb[ST_XSN + k*13 + tid] = XIl[tid];

    float4 xn = x;
#pragma unroll
    for (int j = 0; j < 12; ++j)
        if (j < k) {
            float fc = nphi[j];
            xn.x = fmaf(fc, G[j].x, xn.x); xn.y = fmaf(fc, G[j].y, xn.y);
            xn.z = fmaf(fc, G[j].z, xn.z); xn.w = fmaf(fc, G[j].w, xn.w);
        }
    {
        float fk = nphi[k];
        xn.x = fmaf(fk, gk.x, xn.x); xn.y = fmaf(fk, gk.y, xn.y);
        xn.z = fmaf(fk, gk.z, xn.z); xn.w = fmaf(fk, gk.w, xn.w);
    }

    *(float4*)(gxp + (size_t)k * BD + base) = gk;

    float a[4] = {xn.x, xn.y, xn.z, xn.w};
    ushort_t hh[4], ll[4];
#pragma unroll
    for (int j = 0; j < 4; ++j) { hh[j] = f2bf(a[j]); ll[j] = f2bf(a[j] - bf2f(hh[j])); }
    ushort4 h = {hh[0],hh[1],hh[2],hh[3]}, l = {ll[0],ll[1],ll[2],ll[3]};
    size_t ab = (size_t)b * KK + col;
    *(ushort4*)(Azz + ab) = h; *(ushort4*)(Azz + ab + DD) = h; *(ushort4*)(Azz + ab + 2*DD) = l;
}

// ---------------- final: argmin obj; out = x_bk + g_bk ----------------
__global__ __launch_bounds__(256)
void final_out(const float* __restrict__ gxp, const float* __restrict__ state,
               const float* __restrict__ scal, float* __restrict__ out) {
    const int i4 = blockIdx.x * 256 + threadIdx.x;
    float best = scal[0];
    int bk = 0;
#pragma unroll
    for (int k = 1; k <= TT; ++k) {
        float o = scal[k];
        if (o < best) { best = o; bk = k; }
    }
    const size_t idx = (size_t)i4 * 4;
    const int m = (int)(idx >> 11);
    const float* cf = state + (size_t)m * ST_SZ + ST_XSN + bk * 13;
    float4 r = *(const float4*)(gxp + (size_t)bk * BD + idx);
    for (int j = 0; j < bk; ++j) {
        float c1 = cf[j];
        float4 g = *(const float4*)(gxp + (size_t)j * BD + idx);
        r.x = fmaf(c1, g.x, r.x); r.y = fmaf(c1, g.y, r.y);
        r.z = fmaf(c1, g.z, r.z); r.w = fmaf(c1, g.w, r.w);
    }
    ((float4*)out)[i4] = r;
}

// ---------------- launch ----------------
extern "C" void kernel_launch(void* const* d_in, const int* in_sizes, int n_in,
                              void* d_out, int out_size, void* d_ws, size_t ws_size,
                              hipStream_t stream) {
    const float* xin  = (const float*)d_in[0];
    const float* W    = (const float*)d_in[2];
    const float* U    = (const float*)d_in[3];
    const float* bias = (const float*)d_in[4];
    float* out = (float*)d_out;

    float* ws = (float*)d_ws;
    float* c      = ws;                                   // 1 BD
    float* y      = ws + 1 * (size_t)BD;                  // 8 BD (split-K slices)
    float* gxp    = ws + 9 * (size_t)BD;                  // 13 BD (g_0..g_12)
    ushort_t* Axx = (ushort_t*)(ws + 22 * (size_t)BD);    // 1.5 BD
    ushort_t* Azz = (ushort_t*)(ws + 24 * (size_t)BD);    // 1.5 BD
    ushort_t* Wt  = (ushort_t*)(ws + 26 * (size_t)BD);    // 12 BD
    ushort_t* Ut  = (ushort_t*)(ws + 38 * (size_t)BD);    // 12 BD
    float* state  = ws + 50 * (size_t)BD;                 // 256*1024 = 0.5 BD
    float* scal   = state + (size_t)BB * ST_SZ;           // 32 floats

    convert_w<<<dim3(32, 32, 2), 256, 0, stream>>>(W, U, Wt, Ut);
    init_misc<<<512, 256, 0, stream>>>(xin, Axx, state);

    dim3 gg(32, NKS);   // 256 blocks
    gemm_bf16s<<<gg, 512, 0, stream>>>(Axx, Ut, y);
    epi0<<<BB, 512, 0, stream>>>(y, bias, c, gxp, Azz, state, scal);

    for (int k = 1; k <= TT; ++k) {
        gemm_bf16s<<<gg, 512, 0, stream>>>(Azz, Wt, y);
        broyden_gram<<<BB, 512, 0, stream>>>(y, c, gxp, Azz, state, scal, k);
    }

    final_out<<<512, 256, 0, stream>>>(gxp, state, scal, out);
}

// Round 8
// 419.750 us; speedup vs baseline: 2.5430x; 1.1476x over previous
//
#include <hip/hip_runtime.h>
#include <math.h>

// DEQ fixed-point via Broyden. B=256, D=2048, T=12.
// R8: 2-term split GEMM — A=[x_hi|x_lo] (exact x to 2^-18), W=bf16(W) indexed
// twice -> K=4096 (was 6144). W plane is [2048][2048] u16 (8 MB, L2-friendly).
// M-resident tiling: mtile=256, ntile=64, split-K=8 -> 256 blocks x 512 thr.
// Broyden in Gram/coefficient space (verified R6/R7): 13 gx planes + per-row
// 13-dim coeff state; scalar solve fp64 in-block.

#define DD 2048
#define KA 4096            // A-side K (hi|lo)
#define KW 2048            // W-plane K
#define BB 256
#define BD (BB * DD)
#define TT 12
#define NKS 8              // split-K slices
#define KS 512             // KA/NKS
#define NITER 8            // KS/64

// state layout (floats, per row, stride 1024)
#define ST_S   0           // 169
#define ST_A   169         // 12*13
#define ST_B   325         // 12*13
#define ST_PHI 481         // 13
#define ST_XI  494         // 13
#define ST_XSN 507         // 13*13
#define ST_SZ  1024

typedef unsigned short ushort_t;
typedef __attribute__((ext_vector_type(8))) short short8;
typedef __attribute__((ext_vector_type(4))) float floatx4;

__device__ __forceinline__ ushort_t f2bf(float f) {
    unsigned int u = __float_as_uint(f);
    unsigned int r = (u + 0x7FFFu + ((u >> 16) & 1u)) >> 16;
    return (ushort_t)r;
}
__device__ __forceinline__ float bf2f(ushort_t h) {
    return __uint_as_float(((unsigned int)h) << 16);
}
__device__ __forceinline__ void gload_lds16(const void* g, void* l) {
    __builtin_amdgcn_global_load_lds(
        (const __attribute__((address_space(1))) unsigned int*)g,
        (__attribute__((address_space(3))) unsigned int*)l, 16, 0, 0);
}
__device__ __forceinline__ float wave_red(float v) {
#pragma unroll
    for (int off = 32; off > 0; off >>= 1) v += __shfl_down(v, off, 64);
    return v;
}

// ---------------- W & U -> bf16 transposed [n][k] planes (hi only) ----------------
__global__ __launch_bounds__(256)
void convert_w(const float* __restrict__ W, const float* __restrict__ U,
               ushort_t* __restrict__ Wt, ushort_t* __restrict__ Ut) {
    const float* src = blockIdx.z ? U : W;
    ushort_t* dst = blockIdx.z ? Ut : Wt;
    __shared__ ushort_t Hs[64][65];
    const int tid = threadIdx.x;
    const int k0 = blockIdx.y * 64, n0 = blockIdx.x * 64;
    const int r = tid >> 4, c4 = (tid & 15) * 4;
#pragma unroll
    for (int i = 0; i < 4; ++i) {
        int kr = r + i * 16;
        float4 w = *(const float4*)(src + (size_t)(k0 + kr) * DD + n0 + c4);
        Hs[kr][c4 + 0] = f2bf(w.x); Hs[kr][c4 + 1] = f2bf(w.y);
        Hs[kr][c4 + 2] = f2bf(w.z); Hs[kr][c4 + 3] = f2bf(w.w);
    }
    __syncthreads();
#pragma unroll
    for (int i = 0; i < 4; ++i) {
        int nr = r + i * 16;
        ushort4 hv = { Hs[c4+0][nr], Hs[c4+1][nr], Hs[c4+2][nr], Hs[c4+3][nr] };
        *(ushort4*)(dst + (size_t)(n0 + nr) * KW + (size_t)(k0 + c4)) = hv;
    }
}

// ---------------- init: Axx = [hi|lo](xin); zero state+scal ----------------
__global__ void init_misc(const float* __restrict__ xin, ushort_t* __restrict__ Axx,
                          float* __restrict__ stbase) {
    const int i4 = blockIdx.x * 256 + threadIdx.x;   // 512 blocks
    const int idx = i4 * 4;
    const int m = idx >> 11, col = idx & 2047;
    float4 xv = ((const float4*)xin)[i4];
    float a[4] = {xv.x, xv.y, xv.z, xv.w};
    ushort_t hh[4], ll[4];
#pragma unroll
    for (int j = 0; j < 4; ++j) { hh[j] = f2bf(a[j]); ll[j] = f2bf(a[j] - bf2f(hh[j])); }
    ushort4 h = {hh[0],hh[1],hh[2],hh[3]}, l = {ll[0],ll[1],ll[2],ll[3]};
    size_t ab = (size_t)m * KA + col;
    *(ushort4*)(Axx + ab) = h; *(ushort4*)(Axx + ab + DD) = l;
    if (i4 < 65544) {            // state 256*1024 floats + scal 32
        float4 z = {0.f, 0.f, 0.f, 0.f};
        ((float4*)stbase)[i4] = z;
    }
}

// ---------------- M-resident 2-term split GEMM ----------------
// grid (32, 8): x = n-tile (64), y = ks. Slices 0..3 use A k in [0,2048) (x_hi),
// 4..7 use [2048,4096) (x_lo); W k-offset = (ks&3)*512 both times.
// 512 thr = 8 waves, wave-tile 64x32. A chunk 256x64 (32 KB) + B 64x64 (8 KB), dbuf.
__global__ __launch_bounds__(512)
void gemm_bf16s(const ushort_t* __restrict__ A, const ushort_t* __restrict__ Bt,
                float* __restrict__ y) {
    __shared__ ushort_t As[2][256 * 64];   // 2 x 32 KB
    __shared__ ushort_t Bs[2][64 * 64];    // 2 x 8 KB
    const int tid = threadIdx.x;
    const int lane = tid & 63, w = tid >> 6;
    const int bn = blockIdx.x * 64;
    const int ks = blockIdx.y;
    const int waveM = w >> 1, waveN = w & 1;

    const int srow = tid >> 3;
    const int sg = (tid & 7) ^ (srow & 7);
    const ushort_t* Ag = A  + (size_t)srow * KA + ks * KS + sg * 8;
    const ushort_t* Bg = Bt + (size_t)(bn + srow) * KW + (ks & 3) * KS + sg * 8;
    const size_t rs64 = (size_t)64 * KA;

    const int q = lane >> 4, rl = lane & 15;
    int offA[2][4], offB[2][2];
#pragma unroll
    for (int kk = 0; kk < 2; ++kk) {
        int j = kk * 4 + q;
#pragma unroll
        for (int mi = 0; mi < 4; ++mi) {
            int m = waveM * 64 + mi * 16 + rl;
            offA[kk][mi] = (m * 8 + (j ^ (m & 7))) * 8;
        }
#pragma unroll
        for (int ni = 0; ni < 2; ++ni) {
            int n = waveN * 32 + ni * 16 + rl;
            offB[kk][ni] = (n * 8 + (j ^ (n & 7))) * 8;
        }
    }

    floatx4 acc[4][2];
#pragma unroll
    for (int mi = 0; mi < 4; ++mi)
#pragma unroll
        for (int ni = 0; ni < 2; ++ni) acc[mi][ni] = (floatx4){0.f,0.f,0.f,0.f};

    gload_lds16(Ag,            As[0] + tid * 8);
    gload_lds16(Ag + rs64,     As[0] + (512 + tid) * 8);
    gload_lds16(Ag + 2 * rs64, As[0] + (1024 + tid) * 8);
    gload_lds16(Ag + 3 * rs64, As[0] + (1536 + tid) * 8);
    gload_lds16(Bg,            Bs[0] + tid * 8);
    Ag += 64; Bg += 64;
    __syncthreads();

    for (int it = 0; it < NITER; ++it) {
        const int cur = it & 1, nxt = cur ^ 1;
        if (it + 1 < NITER) {
            gload_lds16(Ag,            As[nxt] + tid * 8);
            gload_lds16(Ag + rs64,     As[nxt] + (512 + tid) * 8);
            gload_lds16(Ag + 2 * rs64, As[nxt] + (1024 + tid) * 8);
            gload_lds16(Ag + 3 * rs64, As[nxt] + (1536 + tid) * 8);
            gload_lds16(Bg,            Bs[nxt] + tid * 8);
            Ag += 64; Bg += 64;
        }
        const ushort_t* Ab = As[cur];
        const ushort_t* Bb = Bs[cur];
#pragma unroll
        for (int kk = 0; kk < 2; ++kk) {
            short8 b0 = *(const short8*)(Bb + offB[kk][0]);
            short8 b1 = *(const short8*)(Bb + offB[kk][1]);
#pragma unroll
            for (int mi = 0; mi < 4; ++mi) {
                short8 a = *(const short8*)(Ab + offA[kk][mi]);
                acc[mi][0] = __builtin_amdgcn_mfma_f32_16x16x32_bf16(a, b0, acc[mi][0], 0, 0, 0);
                acc[mi][1] = __builtin_amdgcn_mfma_f32_16x16x32_bf16(a, b1, acc[mi][1], 0, 0, 0);
            }
        }
        __syncthreads();
    }

    float* yp = y + (size_t)ks * BD;
    const int mb = waveM * 64 + q * 4;
    const int nb = bn + waveN * 32 + rl;
#pragma unroll
    for (int mi = 0; mi < 4; ++mi)
#pragma unroll
        for (int r = 0; r < 4; ++r) {
            yp[(size_t)(mb + mi * 16 + r) * DD + nb]      = acc[mi][0][r];
            yp[(size_t)(mb + mi * 16 + r) * DD + nb + 16] = acc[mi][1][r];
        }
}

// ---------------- step 0: c, g0 = tanh(c), Azz = split(g0), state init ----------------
__global__ __launch_bounds__(512)
void epi0(const float* __restrict__ y, const float* __restrict__ bias,
          float* __restrict__ c, float* __restrict__ gxp,
          ushort_t* __restrict__ Azz, float* __restrict__ state,
          float* __restrict__ scal) {
    __shared__ float red[8];
    const int tid = threadIdx.x;
    const int b = blockIdx.x;
    const int col = tid * 4;
    const size_t base = (size_t)b * DD + col;

    float4 cc = *(const float4*)(bias + col);
#pragma unroll
    for (int s = 0; s < NKS; ++s) {
        float4 v = *(const float4*)(y + (size_t)s * BD + base);
        cc.x += v.x; cc.y += v.y; cc.z += v.z; cc.w += v.w;
    }
    *(float4*)(c + base) = cc;
    float4 g = { tanhf(cc.x), tanhf(cc.y), tanhf(cc.z), tanhf(cc.w) };
    *(float4*)(gxp + base) = g;

    float a[4] = {g.x, g.y, g.z, g.w};
    ushort_t hh[4], ll[4];
#pragma unroll
    for (int j = 0; j < 4; ++j) { hh[j] = f2bf(a[j]); ll[j] = f2bf(a[j] - bf2f(hh[j])); }
    ushort4 h = {hh[0],hh[1],hh[2],hh[3]}, l = {ll[0],ll[1],ll[2],ll[3]};
    size_t ab = (size_t)b * KA + col;
    *(ushort4*)(Azz + ab) = h; *(ushort4*)(Azz + ab + DD) = l;

    float pd = g.x*g.x + g.y*g.y + g.z*g.z + g.w*g.w;
    pd = wave_red(pd);
    if ((tid & 63) == 0) red[tid >> 6] = pd;
    __syncthreads();
    if (tid == 0) {
        float t = 0.f;
#pragma unroll
        for (int w2 = 0; w2 < 8; ++w2) t += red[w2];
        float* stb = state + (size_t)b * ST_SZ;
        stb[ST_S + 0]   = t;
        stb[ST_PHI + 0] = 1.f;
        stb[ST_XI + 0]  = 1.f;
        atomicAdd(&scal[0], t);
    }
}

// ---------------- Gram-space Broyden: one pass over gx planes ----------------
__global__ __launch_bounds__(512)
void broyden_gram(const float* __restrict__ y, const float* __restrict__ c,
                  float* __restrict__ gxp, ushort_t* __restrict__ Azz,
                  float* __restrict__ state, float* __restrict__ scal, int k)
{
    __shared__ float red[8][16];
    __shared__ float dots[14];
    __shared__ float Sl[169], Al[156], Bl[156], PHl[13], XIl[13];
    __shared__ float newA[14], newB[14], nphi[14];
    __shared__ double dyv[13], dxtu[12], dvdg[12], dcgx[13], dden[1];
    const int tid = threadIdx.x;
    const int lane = tid & 63, w = tid >> 6;
    const int b = blockIdx.x;
    const int p = k - 1;
    float* stb = state + (size_t)b * ST_SZ;

    for (int i = tid; i < 169; i += 512) Sl[i] = stb[ST_S + i];
    for (int i = tid; i < 156; i += 512) { Al[i] = stb[ST_A + i]; Bl[i] = stb[ST_B + i]; }
    if (tid < 13) { PHl[tid] = stb[ST_PHI + tid]; XIl[tid] = stb[ST_XI + tid]; }

    const int col = tid * 4;
    const size_t base = (size_t)b * DD + col;
    float4 pre = *(const float4*)(c + base);
#pragma unroll
    for (int s = 0; s < NKS; ++s) {
        float4 v = *(const float4*)(y + (size_t)s * BD + base);
        pre.x += v.x; pre.y += v.y; pre.z += v.z; pre.w += v.w;
    }

    float4 G[12];
#pragma unroll
    for (int j = 0; j < 12; ++j)
        if (j < k) G[j] = *(const float4*)(gxp + (size_t)j * BD + base);

    __syncthreads();

    float4 x = {0.f, 0.f, 0.f, 0.f};
#pragma unroll
    for (int j = 0; j < 12; ++j)
        if (j < k) {
            float xc = XIl[j];
            x.x = fmaf(xc, G[j].x, x.x); x.y = fmaf(xc, G[j].y, x.y);
            x.z = fmaf(xc, G[j].z, x.z); x.w = fmaf(xc, G[j].w, x.w);
        }
    float4 gk = { tanhf(pre.x) - x.x, tanhf(pre.y) - x.y,
                  tanhf(pre.z) - x.z, tanhf(pre.w) - x.w };

#pragma unroll
    for (int j = 0; j < 12; ++j)
        if (j < k) {
            float pd = G[j].x*gk.x + G[j].y*gk.y + G[j].z*gk.z + G[j].w*gk.w;
            pd = wave_red(pd);
            if (lane == 0) red[w][j] = pd;
        }
    {
        float pdk = gk.x*gk.x + gk.y*gk.y + gk.z*gk.z + gk.w*gk.w;
        pdk = wave_red(pdk);
        if (lane == 0) red[w][k] = pdk;
    }
    __syncthreads();
    if (tid <= k) {
        float s = 0.f;
#pragma unroll
        for (int w2 = 0; w2 < 8; ++w2) s += red[w2][tid];
        dots[tid] = s;
        if (tid == k) atomicAdd(&scal[k], s);
    }
    __syncthreads();

    // ---- scalar solve (fp64) ----
    if (tid < k) {
        double s = 0.0;
        for (int j = 0; j < k; ++j) s += (double)Sl[tid*13 + j] * (double)PHl[j];
        dyv[tid] = s;
    }
    __syncthreads();
    if (tid < p) {
        double sx = 0.0, sv = 0.0;
        for (int j = 0; j < k; ++j) {
            sx += (double)Al[tid*13 + j] * dyv[j];
            sv += (double)Bl[tid*13 + j] * ((double)dots[j] - (double)Sl[j*13 + (k-1)]);
        }
        dxtu[tid] = sx; dvdg[tid] = sv;
    }
    __syncthreads();
    if (tid < k) {
        double s = -(double)PHl[tid];
        for (int t = 0; t < p; ++t) s += dxtu[t] * (double)Bl[t*13 + tid];
        newB[tid] = (float)s;
    }
    __syncthreads();
    if (tid == 0) {
        double s = 0.0;
        for (int j = 0; j < k; ++j)
            s += (double)newB[j] * ((double)dots[j] - (double)Sl[j*13 + (k-1)]);
        dden[0] = s;
    }
    __syncthreads();
    if (tid <= k) {
        double s = (double)((tid < 13) ? PHl[tid] : 0.f);
        if (tid == k)     s += 1.0;
        if (tid == k - 1) s -= 1.0;
        for (int t = 0; t < p; ++t) s -= dvdg[t] * (double)Al[t*13 + tid];
        newA[tid] = (float)(s / dden[0]);
    }
    if (tid >= 32 && tid < 32 + p) {
        int t = tid - 32;
        double s = 0.0;
        for (int j = 0; j < k; ++j) s += (double)Bl[t*13 + j] * (double)dots[j];
        dcgx[t] = s;
    }
    if (tid == 63) {
        double s = 0.0;
        for (int j = 0; j < k; ++j) s += (double)newB[j] * (double)dots[j];
        dcgx[p] = s;
    }
    __syncthreads();
    if (tid <= k) {
        double s = (tid == k) ? 1.0 : 0.0;
        for (int t = 0; t < p; ++t) s -= dcgx[t] * (double)Al[t*13 + tid];
        s -= dcgx[p] * (double)newA[tid];
        nphi[tid] = (float)s;
    }
    __syncthreads();

    if (tid <= k) {
        stb[ST_S + k*13 + tid] = dots[tid];
        stb[ST_S + tid*13 + k] = dots[tid];
        stb[ST_A + p*13 + tid] = newA[tid];
        stb[ST_PHI + tid] = nphi[tid];
        float xi_old = (tid < 13) ? XIl[tid] : 0.f;
        stb[ST_XI + tid] = xi_old + nphi[tid];
    }
    if (tid < k) stb[ST_B + p*13 + tid] = newB[tid];
    if (tid < 13) stb[ST_XSN + k*13 + tid] = XIl[tid];

    float4 xn = x;
#pragma unroll
    for (int j = 0; j < 12; ++j)
        if (j < k) {
            float fc = nphi[j];
            xn.x = fmaf(fc, G[j].x, xn.x); xn.y = fmaf(fc, G[j].y, xn.y);
            xn.z = fmaf(fc, G[j].z, xn.z); xn.w = fmaf(fc, G[j].w, xn.w);
        }
    {
        float fk = nphi[k];
        xn.x = fmaf(fk, gk.x, xn.x); xn.y = fmaf(fk, gk.y, xn.y);
        xn.z = fmaf(fk, gk.z, xn.z); xn.w = fmaf(fk, gk.w, xn.w);
    }

    *(float4*)(gxp + (size_t)k * BD + base) = gk;

    float a[4] = {xn.x, xn.y, xn.z, xn.w};
    ushort_t hh[4], ll[4];
#pragma unroll
    for (int j = 0; j < 4; ++j) { hh[j] = f2bf(a[j]); ll[j] = f2bf(a[j] - bf2f(hh[j])); }
    ushort4 h = {hh[0],hh[1],hh[2],hh[3]}, l = {ll[0],ll[1],ll[2],ll[3]};
    size_t ab = (size_t)b * KA + col;
    *(ushort4*)(Azz + ab) = h; *(ushort4*)(Azz + ab + DD) = l;
}

// ---------------- final: argmin obj; out = x_bk + g_bk ----------------
__global__ __launch_bounds__(256)
void final_out(const float* __restrict__ gxp, const float* __restrict__ state,
               const float* __restrict__ scal, float* __restrict__ out) {
    const int i4 = blockIdx.x * 256 + threadIdx.x;
    float best = scal[0];
    int bk = 0;
#pragma unroll
    for (int k = 1; k <= TT; ++k) {
        float o = scal[k];
        if (o < best) { best = o; bk = k; }
    }
    const size_t idx = (size_t)i4 * 4;
    const int m = (int)(idx >> 11);
    const float* cf = state + (size_t)m * ST_SZ + ST_XSN + bk * 13;
    float4 r = *(const float4*)(gxp + (size_t)bk * BD + idx);
    for (int j = 0; j < bk; ++j) {
        float c1 = cf[j];
        float4 g = *(const float4*)(gxp + (size_t)j * BD + idx);
        r.x = fmaf(c1, g.x, r.x); r.y = fmaf(c1, g.y, r.y);
        r.z = fmaf(c1, g.z, r.z); r.w = fmaf(c1, g.w, r.w);
    }
    ((float4*)out)[i4] = r;
}

// ---------------- launch ----------------
extern "C" void kernel_launch(void* const* d_in, const int* in_sizes, int n_in,
                              void* d_out, int out_size, void* d_ws, size_t ws_size,
                              hipStream_t stream) {
    const float* xin  = (const float*)d_in[0];
    const float* W    = (const float*)d_in[2];
    const float* U    = (const float*)d_in[3];
    const float* bias = (const float*)d_in[4];
    float* out = (float*)d_out;

    float* ws = (float*)d_ws;
    float* c      = ws;                                   // 1 BD
    float* y      = ws + 1 * (size_t)BD;                  // 8 BD
    float* gxp    = ws + 9 * (size_t)BD;                  // 13 BD
    ushort_t* Axx = (ushort_t*)(ws + 22 * (size_t)BD);    // [256][4096] u16 = 1 BD
    ushort_t* Azz = (ushort_t*)(ws + 23 * (size_t)BD);    // 1 BD
    ushort_t* Wt  = (ushort_t*)(ws + 24 * (size_t)BD);    // [2048][2048] u16 = 4 BD
    ushort_t* Ut  = (ushort_t*)(ws + 28 * (size_t)BD);    // 4 BD
    float* state  = ws + 32 * (size_t)BD;                 // 0.5 BD
    float* scal   = state + (size_t)BB * ST_SZ;           // 32 floats

    convert_w<<<dim3(32, 32, 2), 256, 0, stream>>>(W, U, Wt, Ut);
    init_misc<<<512, 256, 0, stream>>>(xin, Axx, state);

    dim3 gg(32, NKS);   // 256 blocks
    gemm_bf16s<<<gg, 512, 0, stream>>>(Axx, Ut, y);
    epi0<<<BB, 512, 0, stream>>>(y, bias, c, gxp, Azz, state, scal);

    for (int k = 1; k <= TT; ++k) {
        gemm_bf16s<<<gg, 512, 0, stream>>>(Azz, Wt, y);
        broyden_gram<<<BB, 512, 0, stream>>>(y, c, gxp, Azz, state, scal, k);
    }

    final_out<<<512, 256, 0, stream>>>(gxp, state, scal, out);
}